// Round 4
// baseline (183.114 us; speedup 1.0000x reference)
//
#include <hip/hip_runtime.h>
#include <stdint.h>

// AlbertSeq2Seq fused pipeline, bf16 MFMA. Round 4:
//  - Attention rewritten: global_load_lds DMA staging (pre-swizzled source),
//    double-buffered 1-barrier/tile, l-row-sum via MFMA(P, ones) in o-layout,
//    QK(ts=1) issued before softmax(ts=0), in-place exp2.
//  - transpose_v pair merged into one launch.
//  - GEMMs unchanged (j1 at 2-phase structural ceiling, 857 TF).
// Shapes: B=4, T=S=1024, H=1024, heads=16, d=64.

#define B_   4
#define T_   1024
#define S_   1024
#define H_   1024
#define LOG2E 1.44269504088896340736f
#define SCALE_K (0.125f * LOG2E)

typedef __attribute__((ext_vector_type(8)))  __bf16       bf16x8;
typedef __attribute__((ext_vector_type(4)))  float        f32x4;
typedef __attribute__((ext_vector_type(16))) float        f32x16;
typedef __attribute__((ext_vector_type(4)))  unsigned int uint4v;

static __device__ __forceinline__ float bf2f(unsigned int u) {
    return __builtin_bit_cast(float, u << 16);
}
static __device__ __forceinline__ unsigned short f2bf(float f) {
    unsigned int x = __builtin_bit_cast(unsigned int, f);
    return (unsigned short)((x + 0x7fffu + ((x >> 16) & 1u)) >> 16);
}
static __device__ __forceinline__ unsigned int cvt_pk_bf16(float lo, float hi) {
    unsigned int r;
    asm("v_cvt_pk_bf16_f32 %0, %1, %2" : "=v"(r) : "v"(lo), "v"(hi));
    return r;
}
static __device__ __forceinline__ void perm32swap(unsigned int& a, unsigned int& b) {
    asm("v_permlane32_swap_b32 %0, %1" : "+v"(a), "+v"(b));
}
static __device__ __forceinline__ f32x4 mfma16(bf16x8 a, bf16x8 b, f32x4 c) {
    return __builtin_amdgcn_mfma_f32_16x16x32_bf16(a, b, c, 0, 0, 0);
}
static __device__ __forceinline__ f32x16 mfma32(bf16x8 a, bf16x8 b, f32x16 c) {
    return __builtin_amdgcn_mfma_f32_32x32x16_bf16(a, b, c, 0, 0, 0);
}

typedef const __attribute__((address_space(1))) void gv_t;
typedef __attribute__((address_space(3))) void lv_t;
static __device__ __forceinline__ void g2lds16(const void* g, void* l) {
    __builtin_amdgcn_global_load_lds((gv_t*)(size_t)g, (lv_t*)(unsigned int)(size_t)l, 16, 0, 0);
}

// ---------------- fused fp32 -> bf16 convert (6 tensors, 1 launch) ----------------
struct CvtArgs {
    const float* src[6];
    unsigned short* dst[6];
    float scale[6];
    int n4[6];
};
__global__ __launch_bounds__(256)
void cvt_multi(CvtArgs a) {
    const int k = blockIdx.y;
    const int i = blockIdx.x * 256 + threadIdx.x;
    if (i >= a.n4[k]) return;
    const float s = a.scale[k];
    float4 v = ((const float4*)a.src[k])[i];
    uint2 o;
    o.x = (unsigned)f2bf(v.x * s) | ((unsigned)f2bf(v.y * s) << 16);
    o.y = (unsigned)f2bf(v.z * s) | ((unsigned)f2bf(v.w * s) << 16);
    ((uint2*)a.dst[k])[i] = o;
}

// ---------------- GEMM: O[set] = A[set] @ W[set]^T + bias[set]*bs[set] ----------------
struct GemmJob {
    const unsigned short* A[5];
    const unsigned short* W[5];
    const float* bias[5];
    float bs[5];
    unsigned short* O[5];
};
__global__ __launch_bounds__(256, 2)
void gemm_bf16(GemmJob job)
{
    __shared__ char smem[32768];
    char* As = smem;
    char* Bs = smem + 16384;
    const int tid = threadIdx.x;
    const int lane = tid & 63;
    const int w = tid >> 6;
    const int c = lane & 15, g = lane >> 4;
    const int wm = (w >> 1) * 64, wn = (w & 1) * 64;
    const int m0 = blockIdx.x * 128;
    const int set = blockIdx.y >> 3;
    const int n0 = (blockIdx.y & 7) * 128;
    const unsigned short* A    = job.A[set];
    const unsigned short* W    = job.W[set];
    const float* bias          = job.bias[set];
    const float bscale         = job.bs[set];
    unsigned short* O          = job.O[set];

    f32x4 acc[4][4];
#pragma unroll
    for (int i = 0; i < 4; i++)
#pragma unroll
        for (int j = 0; j < 4; j++) acc[i][j] = (f32x4){0.f, 0.f, 0.f, 0.f};

    const int srow = w * 32 + (lane >> 3);
    const int swzc = ((lane & 7) ^ (lane >> 3)) * 8;
    const unsigned short* gA = A + (size_t)(m0 + srow) * 1024 + swzc;
    const unsigned short* gB = W + (size_t)(n0 + srow) * 1024 + swzc;
    char* lA = As + w * 4096;
    char* lB = Bs + w * 4096;

    for (int kk = 0; kk < 1024; kk += 64) {
#pragma unroll
        for (int q = 0; q < 4; q++) {
            g2lds16(gA + kk + q*8192, lA + q*1024);
            g2lds16(gB + kk + q*8192, lB + q*1024);
        }
        __syncthreads();
#pragma unroll
        for (int ksub = 0; ksub < 2; ksub++) {
            bf16x8 af[4], bfr[4];
#pragma unroll
            for (int t = 0; t < 4; t++) {
                const int ra = wm + t*16 + c;
                const int rb = wn + t*16 + c;
                const int so = ((ksub*4 + g) ^ (c & 7)) << 4;
                af[t]  = *(const bf16x8*)(As + ra*128 + so);
                bfr[t] = *(const bf16x8*)(Bs + rb*128 + so);
            }
#pragma unroll
            for (int i = 0; i < 4; i++)
#pragma unroll
                for (int j = 0; j < 4; j++)
                    acc[i][j] = mfma16(af[i], bfr[j], acc[i][j]);
        }
        __syncthreads();
    }

    float bvv[4];
#pragma unroll
    for (int j = 0; j < 4; j++) bvv[j] = bias[n0 + wn + j*16 + c] * bscale;
    char* eb = As + w * 4096;
#pragma unroll
    for (int p = 0; p < 2; p++) {
#pragma unroll
        for (int ii = 0; ii < 2; ii++) {
            const int i = p*2 + ii;
#pragma unroll
            for (int j = 0; j < 4; j++)
#pragma unroll
                for (int r = 0; r < 4; r++)
                    *(unsigned short*)(eb + (ii*16 + g*4 + r)*128 + (c + j*16)*2)
                        = f2bf(acc[i][j][r] + bvv[j]);
        }
        asm volatile("s_waitcnt lgkmcnt(0)" ::: "memory");
#pragma unroll
        for (int it = 0; it < 4; it++) {
            const int lrow = it*8 + (lane >> 3);
            uint4 vv = *(const uint4*)(eb + lrow*128 + (lane & 7)*16);
            *(uint4*)(O + (size_t)(m0 + wm + p*32 + lrow)*1024 + n0 + wn + (lane & 7)*8) = vv;
        }
        if (p == 0) asm volatile("s_waitcnt lgkmcnt(0)" ::: "memory");
    }
}

// ---------------- per-head V transpose (both tensors, one launch) ----------------
__global__ __launch_bounds__(256)
void transpose_v2(const unsigned short* __restrict__ V0, unsigned short* __restrict__ VT0,
                  const unsigned short* __restrict__ V1, unsigned short* __restrict__ VT1)
{
    __shared__ char sm[8192];
    const unsigned short* V = blockIdx.z ? V1 : V0;
    unsigned short* VT      = blockIdx.z ? VT1 : VT0;
    const int tid = threadIdx.x;
    const int bh = blockIdx.y, b = bh >> 4, h = bh & 15;
    const int s0 = blockIdx.x * 64;
    for (int u = tid; u < 512; u += 256) {
        const int r = u >> 3, sg = u & 7;
        uint4 v = *(const uint4*)(V + (size_t)(b*S_ + s0 + r)*H_ + h*64 + sg*8);
        *(uint4*)(sm + r*128 + ((sg*16) ^ ((r & 7) << 4))) = v;
    }
    __syncthreads();
    const int d = tid >> 2, ss = tid & 3;
    unsigned int ow[8];
#pragma unroll
    for (int j2 = 0; j2 < 8; j2++) {
        const int s_a = ss*16 + 2*j2, s_b = s_a + 1;
        unsigned int ta = *(const unsigned short*)(sm + s_a*128 + ((2*d) ^ ((s_a & 7) << 4)));
        unsigned int tb = *(const unsigned short*)(sm + s_b*128 + ((2*d) ^ ((s_b & 7) << 4)));
        ow[j2] = ta | (tb << 16);
    }
    unsigned short* op = VT + (size_t)(bh*64 + d)*S_ + s0 + ss*16;
    uint4 o0, o1;
    o0.x = ow[0]; o0.y = ow[1]; o0.z = ow[2]; o0.w = ow[3];
    o1.x = ow[4]; o1.y = ow[5]; o1.z = ow[6]; o1.w = ow[7];
    *(uint4*)op = o0;
    *(uint4*)(op + 8) = o1;
}

// ---------------- fused flash attention, round 4 ----------------
// grid (T/128, B*NH), 256 threads = 4 waves, wave owns 32 q-rows.
// K pre-scaled by 0.125*log2e -> P = exp2(S^T) (fixed-shift softmax).
// Staging via global_load_lds with pre-swizzled per-lane SOURCE (linear LDS dest);
// row-sum l accumulated by mfma32(P, ones) directly in o's C-layout.
__global__ __launch_bounds__(256, 4)
void attn_fused3(const unsigned short* __restrict__ Q,
                 const unsigned short* __restrict__ Kx,
                 const unsigned short* __restrict__ VT,
                 const float* __restrict__ mask,
                 unsigned short* __restrict__ Octx)
{
    __shared__ char smem[32768 + 4096 + 16];
    float* mb = (float*)(smem + 32768);
    int* flag = (int*)(smem + 32768 + 4096);

    const int tid = threadIdx.x;
    const int lane = tid & 63, w = tid >> 6;
    const int qc = lane & 31, hi = lane >> 5;
    const int bh = blockIdx.y, b = bh >> 4, h = bh & 15;
    const int q0 = blockIdx.x * 128 + w * 32;

    // staging: thread covers rows rs=tid>>3 and rs+32, seg sg=tid&7.
    // source col pre-swizzled so linear LDS write == swizzled layout LDS[r][s] = G[r][s^(r&7)]
    const int rs = tid >> 3, sg = tid & 7;
    const int scol = (sg ^ (rs & 7)) * 8;
    const unsigned short* gK = Kx + (size_t)(b*S_ + rs)*H_ + h*64 + scol;      // + t*64*H_
    const unsigned short* gV = VT + (size_t)(bh*64 + rs)*S_ + scol;            // + s0
    char* ldK = smem + w * 1024;          // + buf*16384 (+4096 for half1)
    char* ldV = smem + 8192 + w * 1024;

    // Q fragments: B[k=d][col=q]
    const unsigned short* qptr = Q + (size_t)(b*T_ + q0 + qc)*H_ + h*64 + hi*8;
    bf16x8 qf[4];
#pragma unroll
    for (int s = 0; s < 4; s++) qf[s] = *(const bf16x8*)(qptr + s*16);

    // ones B-frag for the l row-sum MFMA
    uint4v onesw;
    onesw[0] = 0x3f803f80u; onesw[1] = 0x3f803f80u; onesw[2] = 0x3f803f80u; onesw[3] = 0x3f803f80u;
    const bf16x8 ones = __builtin_bit_cast(bf16x8, onesw);

    if (tid == 0) *flag = 0;
    // tile 0 staging (buf 0)
    g2lds16(gK,           ldK);
    g2lds16(gK + 32*H_,   ldK + 4096);
    g2lds16(gV,           ldV);
    g2lds16(gV + 32*S_,   ldV + 4096);
    __syncthreads();
    {
        float4 mv = ((const float4*)(mask + (size_t)b*S_))[tid];
        float4 ms;
        ms.x = mv.x * LOG2E; ms.y = mv.y * LOG2E; ms.z = mv.z * LOG2E; ms.w = mv.w * LOG2E;
        ((float4*)mb)[tid] = ms;
        if (mv.x != 0.f || mv.y != 0.f || mv.z != 0.f || mv.w != 0.f) atomicOr(flag, 1);
    }
    __syncthreads();
    const int msk = *flag;

    f32x16 o0 = {}, o1 = {}, lsum = {};

    for (int t = 0; t < 16; ++t) {
        // issue next tile's DMA into the other buffer (safe: its readers finished at t-1's barrier)
        if (t < 15) {
            const int nb = (t + 1) & 1;
            const size_t ko = (size_t)(t + 1) * 64 * H_;
            const int    vo = (t + 1) * 64;
            g2lds16(gK + ko,          ldK + nb*16384);
            g2lds16(gK + ko + 32*H_,  ldK + nb*16384 + 4096);
            g2lds16(gV + vo,          ldV + nb*16384);
            g2lds16(gV + vo + 32*S_,  ldV + nb*16384 + 4096);
        }
        const char* Ks = smem + (t & 1) * 16384;
        const char* Vs = Ks + 8192;

        // ---- QK^T for both 32-s halves up front (st1 latency hides under SM0) ----
        f32x16 st0 = {}, st1 = {};
        __builtin_amdgcn_s_setprio(1);
#pragma unroll
        for (int step = 0; step < 4; ++step) {
            bf16x8 ak = *(const bf16x8*)(Ks + qc*128 + ((step*32 + hi*16) ^ ((qc & 7) << 4)));
            st0 = mfma32(ak, qf[step], st0);
        }
#pragma unroll
        for (int step = 0; step < 4; ++step) {
            bf16x8 ak = *(const bf16x8*)(Ks + (32 + qc)*128 + ((step*32 + hi*16) ^ ((qc & 7) << 4)));
            st1 = mfma32(ak, qf[step], st1);
        }
        __builtin_amdgcn_s_setprio(0);

#pragma unroll
        for (int ts = 0; ts < 2; ++ts) {
            f32x16& st = ts ? st1 : st0;
            // ---- softmax: P = exp2(S + mask*LOG2E), in place ----
            if (msk) {
#pragma unroll
                for (int rq = 0; rq < 4; ++rq) {
                    const float4 bb = *(const float4*)(mb + t*64 + ts*32 + rq*8 + hi*4);
#pragma unroll
                    for (int e = 0; e < 4; ++e)
                        st[rq*4 + e] = __builtin_amdgcn_exp2f(st[rq*4 + e] + (&bb.x)[e]);
                }
            } else {
#pragma unroll
                for (int r = 0; r < 16; ++r) st[r] = __builtin_amdgcn_exp2f(st[r]);
            }

            // ---- P->A-frags (cvt_pk + permlane32_swap) + PV + l-sum ----
#pragma unroll
            for (int half = 0; half < 2; ++half) {
                unsigned w0 = cvt_pk_bf16(st[half*8 + 0], st[half*8 + 1]);
                unsigned w1 = cvt_pk_bf16(st[half*8 + 2], st[half*8 + 3]);
                unsigned w2 = cvt_pk_bf16(st[half*8 + 4], st[half*8 + 5]);
                unsigned w3 = cvt_pk_bf16(st[half*8 + 6], st[half*8 + 7]);
                perm32swap(w0, w2);
                perm32swap(w1, w3);
                uint4v fw; fw[0] = w0; fw[1] = w1; fw[2] = w2; fw[3] = w3;
                const bf16x8 pa = __builtin_bit_cast(bf16x8, fw);
                const int vcol = (ts*64 + half*32 + hi*16) ^ ((qc & 7) << 4);
                bf16x8 v0 = *(const bf16x8*)(Vs + qc*128        + vcol);
                bf16x8 v1 = *(const bf16x8*)(Vs + (32 + qc)*128 + vcol);
                __builtin_amdgcn_s_setprio(1);
                o0   = mfma32(pa, v0,   o0);
                o1   = mfma32(pa, v1,   o1);
                lsum = mfma32(pa, ones, lsum);
                __builtin_amdgcn_s_setprio(0);
            }
        }
        __syncthreads();   // drains this iteration's DMA (t+1 tile) + protects dbuf reuse
    }

    // ---- epilogue: normalize by lsum (same C-layout as o) and store ----
#pragma unroll
    for (int dt = 0; dt < 2; ++dt) {
        const f32x16& oo = dt ? o1 : o0;
#pragma unroll
        for (int r = 0; r < 16; ++r) {
            const int qrow = (r & 3) + 8*(r >> 2) + 4*hi;
            const float val = oo[r] / lsum[r];
            Octx[(size_t)(b*T_ + q0 + qrow)*H_ + h*64 + dt*32 + qc] = f2bf(val);
        }
    }
}

// ---------------- residual + LayerNorm ----------------
template<int OUTMODE>   // 0: bf16 out, 1: f32 out
__global__ __launch_bounds__(256)
void ln_kernel(const unsigned short* __restrict__ resid,
               const unsigned short* __restrict__ proj,
               const float* __restrict__ gam,
               const float* __restrict__ bet,
               unsigned short* __restrict__ obf,
               float* __restrict__ of32)
{
    __shared__ float red[8];
    const int tid = threadIdx.x;
    const int lane = tid & 63, w = tid >> 6;
    const int i = tid * 4;
    const size_t base = (size_t)blockIdx.x * 1024 + i;
    uint2 rv = *(const uint2*)(resid + base);
    uint2 pv = *(const uint2*)(proj + base);
    float x[4];
    x[0] = bf2f(rv.x & 0xffffu) + bf2f(pv.x & 0xffffu);
    x[1] = bf2f(rv.x >> 16)     + bf2f(pv.x >> 16);
    x[2] = bf2f(rv.y & 0xffffu) + bf2f(pv.y & 0xffffu);
    x[3] = bf2f(rv.y >> 16)     + bf2f(pv.y >> 16);
    float s = x[0] + x[1] + x[2] + x[3];
    float q = x[0]*x[0] + x[1]*x[1] + x[2]*x[2] + x[3]*x[3];
#pragma unroll
    for (int off = 1; off < 64; off <<= 1) {
        s += __shfl_xor(s, off);
        q += __shfl_xor(q, off);
    }
    if (lane == 0) { red[w*2] = s; red[w*2 + 1] = q; }
    __syncthreads();
    s = red[0] + red[2] + red[4] + red[6];
    q = red[1] + red[3] + red[5] + red[7];
    const float mu   = s * (1.f/1024.f);
    const float var  = q * (1.f/1024.f) - mu*mu;
    const float rstd = rsqrtf(var + 1e-12f);
    const float4 gv = *(const float4*)(gam + i);
    const float4 bv = *(const float4*)(bet + i);
    float y[4];
#pragma unroll
    for (int j = 0; j < 4; j++)
        y[j] = (x[j] - mu) * rstd * (&gv.x)[j] + (&bv.x)[j];
    if (OUTMODE == 0) {
        uint2 oo;
        oo.x = (unsigned)f2bf(y[0]) | ((unsigned)f2bf(y[1]) << 16);
        oo.y = (unsigned)f2bf(y[2]) | ((unsigned)f2bf(y[3]) << 16);
        *(uint2*)(obf + base) = oo;
    } else {
        float4 oo; oo.x = y[0]; oo.y = y[1]; oo.z = y[2]; oo.w = y[3];
        *(float4*)(of32 + base) = oo;
    }
}

extern "C" void kernel_launch(void* const* d_in, const int* in_sizes, int n_in,
                              void* d_out, int out_size, void* d_ws, size_t ws_size,
                              hipStream_t stream)
{
    const float* enc   = (const float*)d_in[0];
    const float* dec   = (const float*)d_in[1];
    const float* smask = (const float*)d_in[2];
    const float* tmask = (const float*)d_in[3];
    const float* Wq = (const float*)d_in[4];
    const float* bq = (const float*)d_in[5];
    const float* Wk = (const float*)d_in[6];
    const float* bk = (const float*)d_in[7];
    const float* Wv = (const float*)d_in[8];
    const float* bv = (const float*)d_in[9];
    const float* Wd = (const float*)d_in[10];
    const float* bd = (const float*)d_in[11];
    const float* lng = (const float*)d_in[12];
    const float* lnb = (const float*)d_in[13];
    float* out = (float*)d_out;

    char* ws = (char*)d_ws;
    const size_t MB = 1024ull * 1024ull;
    unsigned short* dec_bf = (unsigned short*)(ws + 0*MB);
    unsigned short* enc_bf = (unsigned short*)(ws + 8*MB);
    unsigned short* Wq_bf  = (unsigned short*)(ws + 16*MB);
    unsigned short* Wk_bf  = (unsigned short*)(ws + 18*MB);
    unsigned short* Wv_bf  = (unsigned short*)(ws + 20*MB);
    unsigned short* Wd_bf  = (unsigned short*)(ws + 22*MB);
    unsigned short* q1  = (unsigned short*)(ws + 24*MB);
    unsigned short* k1  = (unsigned short*)(ws + 32*MB);
    unsigned short* v1  = (unsigned short*)(ws + 40*MB);
    unsigned short* ek  = (unsigned short*)(ws + 48*MB);
    unsigned short* ev  = (unsigned short*)(ws + 56*MB);
    unsigned short* vt1 = (unsigned short*)(ws + 64*MB);
    unsigned short* ctx      = dec_bf;
    unsigned short* proj     = enc_bf;
    unsigned short* self_out = k1;
    unsigned short* evt      = v1;

    CvtArgs ca;
    ca.src[0] = dec; ca.dst[0] = dec_bf; ca.scale[0] = 1.f;      ca.n4[0] = 1048576;
    ca.src[1] = enc; ca.dst[1] = enc_bf; ca.scale[1] = 1.f;      ca.n4[1] = 1048576;
    ca.src[2] = Wq;  ca.dst[2] = Wq_bf;  ca.scale[2] = 1.f;      ca.n4[2] = 262144;
    ca.src[3] = Wk;  ca.dst[3] = Wk_bf;  ca.scale[3] = SCALE_K;  ca.n4[3] = 262144;
    ca.src[4] = Wv;  ca.dst[4] = Wv_bf;  ca.scale[4] = 1.f;      ca.n4[4] = 262144;
    ca.src[5] = Wd;  ca.dst[5] = Wd_bf;  ca.scale[5] = 1.f;      ca.n4[5] = 262144;
    cvt_multi<<<dim3(4096, 6), 256, 0, stream>>>(ca);

    GemmJob j1;
    j1.A[0] = dec_bf; j1.W[0] = Wq_bf; j1.bias[0] = bq; j1.bs[0] = 1.f;     j1.O[0] = q1;
    j1.A[1] = dec_bf; j1.W[1] = Wk_bf; j1.bias[1] = bk; j1.bs[1] = SCALE_K; j1.O[1] = k1;
    j1.A[2] = dec_bf; j1.W[2] = Wv_bf; j1.bias[2] = bv; j1.bs[2] = 1.f;     j1.O[2] = v1;
    j1.A[3] = enc_bf; j1.W[3] = Wk_bf; j1.bias[3] = bk; j1.bs[3] = SCALE_K; j1.O[3] = ek;
    j1.A[4] = enc_bf; j1.W[4] = Wv_bf; j1.bias[4] = bv; j1.bs[4] = 1.f;     j1.O[4] = ev;
    gemm_bf16<<<dim3(32, 40), 256, 0, stream>>>(j1);

    transpose_v2<<<dim3(16, 64, 2), 256, 0, stream>>>(v1, vt1, ev, evt);

    GemmJob jd;
    for (int i = 0; i < 5; i++) {
        jd.A[i] = ctx; jd.W[i] = Wd_bf; jd.bias[i] = bd; jd.bs[i] = 1.f; jd.O[i] = proj;
    }

    // self-attention
    attn_fused3<<<dim3(8, 64), 256, 0, stream>>>(q1, k1, vt1, tmask, ctx);
    gemm_bf16<<<dim3(32, 8), 256, 0, stream>>>(jd);
    ln_kernel<0><<<4096, 256, 0, stream>>>(q1, proj, lng, lnb, self_out, nullptr);

    // cross-attention (query = self_out directly)
    attn_fused3<<<dim3(8, 64), 256, 0, stream>>>(self_out, ek, evt, smask, ctx);
    gemm_bf16<<<dim3(32, 8), 256, 0, stream>>>(jd);
    ln_kernel<1><<<4096, 256, 0, stream>>>(self_out, proj, lng, lnb, nullptr, out);
}